// Round 13
// baseline (582.978 us; speedup 1.0000x reference)
//
#include <hip/hip_runtime.h>
#include <math.h>

#define BB 4
#define LL 512
#define DD 256
#define HH 8
#define DHH 32
#define NB 12  // BUCKETS + 1 (row 11 is the zero padding row)

// K1: QKV projections (8-row tiles, 768 blocks = 3 blocks/CU).
// Thread = 2 rows x 4 cols; W loads batched 8-deep for MLP.
__global__ __launch_bounds__(256) void qkv_kernel(const float* __restrict__ x,
    const float* __restrict__ Wq, const float* __restrict__ bq,
    const float* __restrict__ Wk, const float* __restrict__ bk,
    const float* __restrict__ Wv, const float* __restrict__ bv,
    const float* __restrict__ uvec, const float* __restrict__ vvec,
    float* __restrict__ Qu, float* __restrict__ Qv,
    float* __restrict__ KT, float* __restrict__ V) {
    __shared__ float xs[8][DD];
    const int mat = blockIdx.x >> 8;          // 0=Q, 1=K, 2=V
    const int r0 = (blockIdx.x & 255) * 8;
    const int t = threadIdx.x;
    const int cg = t & 63, rg = t >> 6;
    const int c0 = cg * 4;
    {
        const float4* xg = (const float4*)(x + r0 * DD);
        float4* xsv = (float4*)&xs[0][0];
        xsv[t] = xg[t];
        xsv[t + 256] = xg[t + 256];
    }
    __syncthreads();
    const float* W    = (mat == 0) ? Wq : (mat == 1) ? Wk : Wv;
    const float* bias = (mat == 0) ? bq : (mat == 1) ? bk : bv;
    float acc[2][4];
#pragma unroll
    for (int r = 0; r < 2; ++r)
#pragma unroll
        for (int c = 0; c < 4; ++c) acc[r][c] = bias[c0 + c];
    for (int i0 = 0; i0 < DD; i0 += 8) {
        float4 wv4[8], xa[2], xb[2];
#pragma unroll
        for (int j = 0; j < 8; ++j) wv4[j] = *(const float4*)&W[(i0 + j) * DD + c0];
#pragma unroll
        for (int r = 0; r < 2; ++r) {
            xa[r] = *(const float4*)&xs[rg * 2 + r][i0];
            xb[r] = *(const float4*)&xs[rg * 2 + r][i0 + 4];
        }
#pragma unroll
        for (int r = 0; r < 2; ++r) {
            const float* xf = (const float*)&xa[r];
            const float* xg2 = (const float*)&xb[r];
#pragma unroll
            for (int j = 0; j < 4; ++j)
#pragma unroll
                for (int c = 0; c < 4; ++c)
                    acc[r][c] = fmaf(xf[j], ((const float*)&wv4[j])[c], acc[r][c]);
#pragma unroll
            for (int j = 0; j < 4; ++j)
#pragma unroll
                for (int c = 0; c < 4; ++c)
                    acc[r][c] = fmaf(xg2[j], ((const float*)&wv4[j + 4])[c], acc[r][c]);
        }
    }
    if (mat == 0) {
        const float s = 0.17677669529663687f;  // 1/sqrt(DH)
        const float4 u4 = *(const float4*)&uvec[c0];
        const float4 v4 = *(const float4*)&vvec[c0];
#pragma unroll
        for (int r = 0; r < 2; ++r) {
            const int row = r0 + rg * 2 + r;
            float4 q = make_float4(acc[r][0] * s, acc[r][1] * s, acc[r][2] * s, acc[r][3] * s);
            *(float4*)&Qu[row * DD + c0] = make_float4(q.x + u4.x, q.y + u4.y, q.z + u4.z, q.w + u4.w);
            *(float4*)&Qv[row * DD + c0] = make_float4(q.x + v4.x, q.y + v4.y, q.z + v4.z, q.w + v4.w);
        }
    } else if (mat == 1) {
        const int b = r0 >> 9;
        const int kb = (r0 & 511) + rg * 2;
#pragma unroll
        for (int c = 0; c < 4; ++c) {
            const int col = c0 + c;
            const int h = col >> 5, dd = col & 31;
            float* p = KT + ((long)((b * HH + h) * DHH + dd)) * LL + kb;
            p[0] = acc[0][c];
            p[1] = acc[1][c];
        }
    } else {
#pragma unroll
        for (int r = 0; r < 2; ++r)
            *(float4*)&V[(r0 + rg * 2 + r) * DD + c0] =
                make_float4(acc[r][0], acc[r][1], acc[r][2], acc[r][3]);
    }
}

// K2: fused rel-P + scores + softmax + attn write + ctx.
// Phase A (NEW): thread t owns k-column t for ALL 16 q rows -> K fragment kd[32]
// loaded ONCE per thread (lane-coalesced b32 from KT). K traffic per block:
// 64 KB (was 512 KB: each wave privately streamed all k). Mask folded into the
// score base as -1e30 (expf underflows to exact 0 == old ternary semantics).
// Softmax: per-row 64-lane shuffle reduce -> wsum[16][8] -> ONE barrier ->
// broadcast-read inverses. No max-subtraction (scores bounded ~±1).
// Phase B (round-12, unchanged): V staged per 128-k chunk into Vs[32][133];
// thread=(q,d) streams Ss/Vs via b128.
__global__ __launch_bounds__(512, 4) void scores_ctx_kernel(const float* __restrict__ Qu,
    const float* __restrict__ Qv, const float* __restrict__ KT,
    const float* __restrict__ rel_table, const int* __restrict__ mask,
    const int* __restrict__ dist, const float* __restrict__ V,
    float* __restrict__ attn, float* __restrict__ ctx) {
    __shared__ float Qs[16][DHH];
    __shared__ float Qv8[16][DHH];
    __shared__ float rels[NB][DHH + 1];
    __shared__ float Ps[16][NB];
    __shared__ float wsum[16][8];
    __shared__ float Ss[16][4][132];    // attn tile, 4 k-chunks of 128 (+pad)
    __shared__ float Vs[DHH][133];      // V chunk, transposed [d][k] (+pad)
    const int blk = blockIdx.x;         // ((b*32 + qt)*8 + h)
    const int h = blk & 7;
    const int rest = blk >> 3;
    const int qt = rest & 31;
    const int b = rest >> 5;
    const int q0 = qt * 16;
    const int t = threadIdx.x;          // == k column in phase A
    const int w = t >> 6, l = t & 63;

    {
        const int r = t >> 5, c = t & 31;
        Qs[r][c]  = Qu[(b * LL + q0 + r) * DD + h * DHH + c];
        Qv8[r][c] = Qv[(b * LL + q0 + r) * DD + h * DHH + c];
    }
    if (t < NB * DHH) {
        rels[t >> 5][t & 31] = rel_table[(t >> 5) * DD + h * DHH + (t & 31)];
    }
    __syncthreads();
    if (t < 16 * NB) {                  // Ps[r][bk] = dot32(Qv8[r], rels[bk])
        const int bk = t >> 4, r = t & 15;
        float a = 0.f;
#pragma unroll
        for (int d = 0; d < DHH; ++d) a = fmaf(Qv8[r][d], rels[bk][d], a);
        Ps[r][bk] = a;
    }
    __syncthreads();

    // ---- Phase A ----
    float kd[DHH];                      // K column k=t, lane-coalesced
    {
        const float* ktp = KT + (long)(b * HH + h) * DHH * LL + t;
#pragma unroll
        for (int j = 0; j < DHH; ++j) kd[j] = ktp[(long)j * LL];
    }
    float e[16];
    {
        float base[16];                 // Ps gather + mask fold (saves 32 VGPRs vs dv/mv)
#pragma unroll
        for (int r = 0; r < 16; ++r) {
            const int mq = (b * LL + q0 + r) * LL + t;
            const int dv = dist[mq];
            const int mv = mask[mq];
            base[r] = mv ? -1e30f : Ps[r][dv];   // expf(-1e30+s) == 0 exactly
        }
#pragma unroll
        for (int r = 0; r < 16; ++r) {
            float acc = base[r];
            const float4* qup = (const float4*)&Qs[r][0];   // wave-uniform broadcast
#pragma unroll
            for (int j = 0; j < 8; ++j) {
                const float4 qq = qup[j];
                acc = fmaf(qq.x, kd[4 * j + 0], acc);
                acc = fmaf(qq.y, kd[4 * j + 1], acc);
                acc = fmaf(qq.z, kd[4 * j + 2], acc);
                acc = fmaf(qq.w, kd[4 * j + 3], acc);
            }
            e[r] = __expf(acc);
        }
    }
#pragma unroll
    for (int r = 0; r < 16; ++r) {      // per-row wave sum over this wave's 64 k
        float s = e[r];
        for (int off = 32; off > 0; off >>= 1) s += __shfl_xor(s, off);
        if (l == 0) wsum[r][w] = s;
    }
    __syncthreads();
    const int chA = t >> 7, offA = t & 127;
    float* ag = attn + ((long)(b * HH + h) * LL + q0) * LL + t;
#pragma unroll
    for (int r = 0; r < 16; ++r) {
        const float4 s0 = *(const float4*)&wsum[r][0];      // broadcast
        const float4 s1 = *(const float4*)&wsum[r][4];
        const float inv = 1.0f / ((s0.x + s0.y + s0.z + s0.w) +
                                  (s1.x + s1.y + s1.z + s1.w));
        const float a = e[r] * inv;
        ag[(long)r * LL] = a;           // coalesced b32 (lane = k)
        Ss[r][chA][offA] = a;           // 2-way bank alias = free
    }

    // ---- Phase B: ctx via LDS-staged V chunks (round-12 structure) ----
    const int qB = t >> 5;              // 0..15
    const int dB = t & 31;
    const int kkS = t >> 2;             // staging row 0..127
    const int dqS = (t & 3) * 8;        // staging d-group of 8
    float acc = 0.f;
    for (int c = 0; c < 4; ++c) {
        __syncthreads();                // prev compute done (and Ss ready at c=0)
        {   // stage V[b][c*128+kk][h*32+dq..dq+7] -> Vs[d][kk] (transposed)
            const float* vg = V + ((long)(b * LL + c * 128 + kkS)) * DD + h * DHH + dqS;
            const float4 va = *(const float4*)&vg[0];
            const float4 vb4 = *(const float4*)&vg[4];
            Vs[dqS + 0][kkS] = va.x;  Vs[dqS + 1][kkS] = va.y;
            Vs[dqS + 2][kkS] = va.z;  Vs[dqS + 3][kkS] = va.w;
            Vs[dqS + 4][kkS] = vb4.x; Vs[dqS + 5][kkS] = vb4.y;
            Vs[dqS + 6][kkS] = vb4.z; Vs[dqS + 7][kkS] = vb4.w;
        }
        __syncthreads();
#pragma unroll
        for (int j = 0; j < 32; ++j) {  // 4 k per iter
            const float4 sv = *(const float4*)&Ss[qB][c][4 * j];   // wave-broadcast
            const float4 vv = *(const float4*)&Vs[dB][4 * j];      // conflict-free (pad 133)
            acc = fmaf(sv.x, vv.x, fmaf(sv.y, vv.y, fmaf(sv.z, vv.z, fmaf(sv.w, vv.w, acc))));
        }
    }
    ctx[(b * LL + q0 + qB) * DD + h * DHH + dB] = acc;
}

// K3: output projection. Block = 4 rows (512 blocks); thread = 1 row x 4 cols.
__global__ __launch_bounds__(256) void outproj_kernel(const float* __restrict__ ctx,
    const float* __restrict__ Wo, const float* __restrict__ bo,
    float* __restrict__ out) {
    __shared__ float xs[4][DD];
    const int r0 = blockIdx.x * 4;
    const int t = threadIdx.x;
    const int rg = t >> 6;
    const int c0 = (t & 63) * 4;
    ((float4*)&xs[0][0])[t] = ((const float4*)(ctx + r0 * DD))[t];
    __syncthreads();
    float4 acc = *(const float4*)&bo[c0];
    for (int i0 = 0; i0 < DD; i0 += 8) {
        float4 wv[8];
#pragma unroll
        for (int j = 0; j < 8; ++j) wv[j] = *(const float4*)&Wo[(i0 + j) * DD + c0];
        const float4 x0 = *(const float4*)&xs[rg][i0];
        const float4 x1 = *(const float4*)&xs[rg][i0 + 4];
        const float* xf0 = (const float*)&x0;
        const float* xf1 = (const float*)&x1;
#pragma unroll
        for (int j = 0; j < 4; ++j) {
            acc.x = fmaf(xf0[j], wv[j].x, acc.x);
            acc.y = fmaf(xf0[j], wv[j].y, acc.y);
            acc.z = fmaf(xf0[j], wv[j].z, acc.z);
            acc.w = fmaf(xf0[j], wv[j].w, acc.w);
        }
#pragma unroll
        for (int j = 0; j < 4; ++j) {
            acc.x = fmaf(xf1[j], wv[j + 4].x, acc.x);
            acc.y = fmaf(xf1[j], wv[j + 4].y, acc.y);
            acc.z = fmaf(xf1[j], wv[j + 4].z, acc.z);
            acc.w = fmaf(xf1[j], wv[j + 4].w, acc.w);
        }
    }
    *(float4*)&out[(r0 + rg) * DD + c0] = acc;
}

extern "C" void kernel_launch(void* const* d_in, const int* in_sizes, int n_in,
                              void* d_out, int out_size, void* d_ws, size_t ws_size,
                              hipStream_t stream) {
    const float* x    = (const float*)d_in[0];
    const int* mk     = (const int*)d_in[1];   // jax bool -> int32
    const int* dist   = (const int*)d_in[2];
    const float* Wq = (const float*)d_in[3];
    const float* bq = (const float*)d_in[4];
    const float* Wk = (const float*)d_in[5];
    const float* bk = (const float*)d_in[6];
    const float* Wv = (const float*)d_in[7];
    const float* bv = (const float*)d_in[8];
    const float* Wo = (const float*)d_in[9];
    const float* bo = (const float*)d_in[10];
    const float* rel_table = (const float*)d_in[11];
    const float* uvec = (const float*)d_in[12];
    const float* vvec = (const float*)d_in[13];

    float* out  = (float*)d_out;                 // (B,L,D)
    float* attn = out + BB * LL * DD;            // (B,H,L,L)

    float* Qu = (float*)d_ws;                    // q/sqrt(dh) + u
    float* Qv = Qu + BB * LL * DD;               // q/sqrt(dh) + v
    float* KT = Qv + BB * LL * DD;               // [B][H][DH][L]
    float* V  = KT + BB * LL * DD;               // [B][L][D]
    float* C  = V + BB * LL * DD;                // ctx (B,L,D); 10.5 MB ws total

    qkv_kernel<<<3 * 256, 256, 0, stream>>>(x, Wq, bq, Wk, bk, Wv, bv, uvec, vvec,
                                            Qu, Qv, KT, V);
    scores_ctx_kernel<<<BB * (LL / 16) * HH, 512, 0, stream>>>(Qu, Qv, KT, rel_table,
                                                               mk, dist, V, attn, C);
    outproj_kernel<<<BB * LL / 4, 256, 0, stream>>>(C, Wo, bo, out);
}

// Round 14
// 200.354 us; speedup vs baseline: 2.9097x; 2.9097x over previous
//
#include <hip/hip_runtime.h>
#include <math.h>

#define BB 4
#define LL 512
#define DD 256
#define HH 8
#define DHH 32
#define NB 12  // BUCKETS + 1 (row 11 is the zero padding row)

// K1: QKV projections (round-12 exact). 8-row tiles, 768 blocks = 3 blocks/CU.
__global__ __launch_bounds__(256) void qkv_kernel(const float* __restrict__ x,
    const float* __restrict__ Wq, const float* __restrict__ bq,
    const float* __restrict__ Wk, const float* __restrict__ bk,
    const float* __restrict__ Wv, const float* __restrict__ bv,
    const float* __restrict__ uvec, const float* __restrict__ vvec,
    float* __restrict__ Qu, float* __restrict__ Qv,
    float* __restrict__ KT, float* __restrict__ V) {
    __shared__ float xs[8][DD];
    const int mat = blockIdx.x >> 8;          // 0=Q, 1=K, 2=V
    const int r0 = (blockIdx.x & 255) * 8;
    const int t = threadIdx.x;
    const int cg = t & 63, rg = t >> 6;
    const int c0 = cg * 4;
    {
        const float4* xg = (const float4*)(x + r0 * DD);
        float4* xsv = (float4*)&xs[0][0];
        xsv[t] = xg[t];
        xsv[t + 256] = xg[t + 256];
    }
    __syncthreads();
    const float* W    = (mat == 0) ? Wq : (mat == 1) ? Wk : Wv;
    const float* bias = (mat == 0) ? bq : (mat == 1) ? bk : bv;
    float acc[2][4];
#pragma unroll
    for (int r = 0; r < 2; ++r)
#pragma unroll
        for (int c = 0; c < 4; ++c) acc[r][c] = bias[c0 + c];
    for (int i0 = 0; i0 < DD; i0 += 4) {
        float4 wv4[4], xv4[2];
#pragma unroll
        for (int j = 0; j < 4; ++j) wv4[j] = *(const float4*)&W[(i0 + j) * DD + c0];
#pragma unroll
        for (int r = 0; r < 2; ++r) xv4[r] = *(const float4*)&xs[rg * 2 + r][i0];
        const float* wf = (const float*)wv4;
        const float* xf = (const float*)xv4;
#pragma unroll
        for (int r = 0; r < 2; ++r)
#pragma unroll
            for (int j = 0; j < 4; ++j)
#pragma unroll
                for (int c = 0; c < 4; ++c)
                    acc[r][c] = fmaf(xf[r * 4 + j], wf[j * 4 + c], acc[r][c]);
    }
    if (mat == 0) {
        const float s = 0.17677669529663687f;  // 1/sqrt(DH)
        const float4 u4 = *(const float4*)&uvec[c0];
        const float4 v4 = *(const float4*)&vvec[c0];
#pragma unroll
        for (int r = 0; r < 2; ++r) {
            const int row = r0 + rg * 2 + r;
            float4 q = make_float4(acc[r][0] * s, acc[r][1] * s, acc[r][2] * s, acc[r][3] * s);
            *(float4*)&Qu[row * DD + c0] = make_float4(q.x + u4.x, q.y + u4.y, q.z + u4.z, q.w + u4.w);
            *(float4*)&Qv[row * DD + c0] = make_float4(q.x + v4.x, q.y + v4.y, q.z + v4.z, q.w + v4.w);
        }
    } else if (mat == 1) {
        const int b = r0 >> 9;
        const int kb = (r0 & 511) + rg * 2;
#pragma unroll
        for (int c = 0; c < 4; ++c) {
            const int col = c0 + c;
            const int h = col >> 5, dd = col & 31;
            float* p = KT + ((long)((b * HH + h) * DHH + dd)) * LL + kb;
            p[0] = acc[0][c];
            p[1] = acc[1][c];
        }
    } else {
#pragma unroll
        for (int r = 0; r < 2; ++r)
            *(float4*)&V[(r0 + rg * 2 + r) * DD + c0] =
                make_float4(acc[r][0], acc[r][1], acc[r][2], acc[r][3]);
    }
}

// K2: fused rel-P + scores + softmax + attn write + ctx.
// Phase A: thread t owns k-column t for ALL 16 q rows (K fragment kd[32] loaded
// once, lane-coalesced). Per row: score -> e -> IMMEDIATE Ss store + shuffle
// reduce (e dead before next row: no e[16]/base[16] arrays -> no scratch spill,
// the round-13 failure). After barrier: normalize by re-reading own Ss slot,
// write global attn + normalized Ss. Mask folds to -1e30 (expf -> exact 0).
// Phase B (round-12 exact): V staged per 128-k chunk into Vs[32][133].
__global__ __launch_bounds__(512, 4) void scores_ctx_kernel(const float* __restrict__ Qu,
    const float* __restrict__ Qv, const float* __restrict__ KT,
    const float* __restrict__ rel_table, const int* __restrict__ mask,
    const int* __restrict__ dist, const float* __restrict__ V,
    float* __restrict__ attn, float* __restrict__ ctx) {
    __shared__ float Qs[16][DHH];
    __shared__ float Qv8[16][DHH];
    __shared__ float rels[NB][DHH + 1];
    __shared__ float Ps[16][NB];
    __shared__ float wsum[16][8];
    __shared__ float Ss[16][4][132];    // attn tile, 4 k-chunks of 128 (+pad)
    __shared__ float Vs[DHH][133];      // V chunk, transposed [d][k] (+pad)
    const int blk = blockIdx.x;         // ((b*32 + qt)*8 + h)
    const int h = blk & 7;
    const int rest = blk >> 3;
    const int qt = rest & 31;
    const int b = rest >> 5;
    const int q0 = qt * 16;
    const int t = threadIdx.x;          // == k column in phase A
    const int w = t >> 6, l = t & 63;

    {
        const int r = t >> 5, c = t & 31;
        Qs[r][c]  = Qu[(b * LL + q0 + r) * DD + h * DHH + c];
        Qv8[r][c] = Qv[(b * LL + q0 + r) * DD + h * DHH + c];
    }
    if (t < NB * DHH) {
        rels[t >> 5][t & 31] = rel_table[(t >> 5) * DD + h * DHH + (t & 31)];
    }
    __syncthreads();
    if (t < 16 * NB) {                  // Ps[r][bk] = dot32(Qv8[r], rels[bk])
        const int bk = t >> 4, r = t & 15;
        float a = 0.f;
#pragma unroll
        for (int d = 0; d < DHH; ++d) a = fmaf(Qv8[r][d], rels[bk][d], a);
        Ps[r][bk] = a;
    }
    __syncthreads();

    // ---- Phase A ----
    float kd[DHH];                      // K column k=t, lane-coalesced (the ONLY array)
    {
        const float* ktp = KT + (long)(b * HH + h) * DHH * LL + t;
#pragma unroll
        for (int j = 0; j < DHH; ++j) kd[j] = ktp[(long)j * LL];
    }
    const int chA = t >> 7, offA = t & 127;
#pragma unroll
    for (int r = 0; r < 16; ++r) {
        const int mq = (b * LL + q0 + r) * LL + t;
        const int dv = dist[mq];
        const int mv = mask[mq];
        float acc = mv ? -1e30f : Ps[r][dv];    // expf(-1e30+s) == 0 exactly
        const float4* qup = (const float4*)&Qs[r][0];   // wave-uniform broadcast
#pragma unroll
        for (int j = 0; j < 8; ++j) {
            const float4 qq = qup[j];
            acc = fmaf(qq.x, kd[4 * j + 0], acc);
            acc = fmaf(qq.y, kd[4 * j + 1], acc);
            acc = fmaf(qq.z, kd[4 * j + 2], acc);
            acc = fmaf(qq.w, kd[4 * j + 3], acc);
        }
        const float e = __expf(acc);
        Ss[r][chA][offA] = e;           // unnormalized; own slot (race-free)
        float s = e;
        for (int off = 32; off > 0; off >>= 1) s += __shfl_xor(s, off);
        if (l == 0) wsum[r][w] = s;
    }
    __syncthreads();
    {
        float* ag = attn + ((long)(b * HH + h) * LL + q0) * LL + t;
#pragma unroll
        for (int r = 0; r < 16; ++r) {
            const float4 s0 = *(const float4*)&wsum[r][0];  // broadcast
            const float4 s1 = *(const float4*)&wsum[r][4];
            const float inv = 1.0f / ((s0.x + s0.y + s0.z + s0.w) +
                                      (s1.x + s1.y + s1.z + s1.w));
            const float a = Ss[r][chA][offA] * inv;
            ag[(long)r * LL] = a;       // coalesced b32 (lane = k)
            Ss[r][chA][offA] = a;       // normalized in place; own slot
        }
    }

    // ---- Phase B: ctx via LDS-staged V chunks (round-12 exact) ----
    const int qB = t >> 5;              // 0..15
    const int dB = t & 31;
    const int kkS = t >> 2;             // staging row 0..127
    const int dqS = (t & 3) * 8;        // staging d-group of 8
    float acc = 0.f;
    for (int c = 0; c < 4; ++c) {
        __syncthreads();                // prev compute done; Ss normalization visible
        {   // stage V[b][c*128+kk][h*32+dq..dq+7] -> Vs[d][kk] (transposed)
            const float* vg = V + ((long)(b * LL + c * 128 + kkS)) * DD + h * DHH + dqS;
            const float4 va = *(const float4*)&vg[0];
            const float4 vb4 = *(const float4*)&vg[4];
            Vs[dqS + 0][kkS] = va.x;  Vs[dqS + 1][kkS] = va.y;
            Vs[dqS + 2][kkS] = va.z;  Vs[dqS + 3][kkS] = va.w;
            Vs[dqS + 4][kkS] = vb4.x; Vs[dqS + 5][kkS] = vb4.y;
            Vs[dqS + 6][kkS] = vb4.z; Vs[dqS + 7][kkS] = vb4.w;
        }
        __syncthreads();
#pragma unroll
        for (int j = 0; j < 32; ++j) {  // 4 k per iter
            const float4 sv = *(const float4*)&Ss[qB][c][4 * j];   // wave-broadcast
            const float4 vv = *(const float4*)&Vs[dB][4 * j];      // conflict-free (pad 133)
            acc = fmaf(sv.x, vv.x, fmaf(sv.y, vv.y, fmaf(sv.z, vv.z, fmaf(sv.w, vv.w, acc))));
        }
    }
    ctx[(b * LL + q0 + qB) * DD + h * DHH + dB] = acc;
}

// K3: output projection (round-12 exact). Block = 4 rows; thread = 1 row x 4 cols.
__global__ __launch_bounds__(256) void outproj_kernel(const float* __restrict__ ctx,
    const float* __restrict__ Wo, const float* __restrict__ bo,
    float* __restrict__ out) {
    __shared__ float xs[4][DD];
    const int r0 = blockIdx.x * 4;
    const int t = threadIdx.x;
    const int rg = t >> 6;
    const int c0 = (t & 63) * 4;
    ((float4*)&xs[0][0])[t] = ((const float4*)(ctx + r0 * DD))[t];
    __syncthreads();
    float4 acc = *(const float4*)&bo[c0];
    for (int i0 = 0; i0 < DD; i0 += 8) {
        float4 wv[8];
#pragma unroll
        for (int j = 0; j < 8; ++j) wv[j] = *(const float4*)&Wo[(i0 + j) * DD + c0];
        const float4 x0 = *(const float4*)&xs[rg][i0];
        const float4 x1 = *(const float4*)&xs[rg][i0 + 4];
        const float* xf0 = (const float*)&x0;
        const float* xf1 = (const float*)&x1;
#pragma unroll
        for (int j = 0; j < 4; ++j) {
            acc.x = fmaf(xf0[j], wv[j].x, acc.x);
            acc.y = fmaf(xf0[j], wv[j].y, acc.y);
            acc.z = fmaf(xf0[j], wv[j].z, acc.z);
            acc.w = fmaf(xf0[j], wv[j].w, acc.w);
        }
#pragma unroll
        for (int j = 0; j < 4; ++j) {
            acc.x = fmaf(xf1[j], wv[j + 4].x, acc.x);
            acc.y = fmaf(xf1[j], wv[j + 4].y, acc.y);
            acc.z = fmaf(xf1[j], wv[j + 4].z, acc.z);
            acc.w = fmaf(xf1[j], wv[j + 4].w, acc.w);
        }
    }
    *(float4*)&out[(r0 + rg) * DD + c0] = acc;
}

extern "C" void kernel_launch(void* const* d_in, const int* in_sizes, int n_in,
                              void* d_out, int out_size, void* d_ws, size_t ws_size,
                              hipStream_t stream) {
    const float* x    = (const float*)d_in[0];
    const int* mk     = (const int*)d_in[1];   // jax bool -> int32
    const int* dist   = (const int*)d_in[2];
    const float* Wq = (const float*)d_in[3];
    const float* bq = (const float*)d_in[4];
    const float* Wk = (const float*)d_in[5];
    const float* bk = (const float*)d_in[6];
    const float* Wv = (const float*)d_in[7];
    const float* bv = (const float*)d_in[8];
    const float* Wo = (const float*)d_in[9];
    const float* bo = (const float*)d_in[10];
    const float* rel_table = (const float*)d_in[11];
    const float* uvec = (const float*)d_in[12];
    const float* vvec = (const float*)d_in[13];

    float* out  = (float*)d_out;                 // (B,L,D)
    float* attn = out + BB * LL * DD;            // (B,H,L,L)

    float* Qu = (float*)d_ws;                    // q/sqrt(dh) + u
    float* Qv = Qu + BB * LL * DD;               // q/sqrt(dh) + v
    float* KT = Qv + BB * LL * DD;               // [B][H][DH][L]
    float* V  = KT + BB * LL * DD;               // [B][L][D]
    float* C  = V + BB * LL * DD;                // ctx (B,L,D); 10.5 MB ws total

    qkv_kernel<<<3 * 256, 256, 0, stream>>>(x, Wq, bq, Wk, bk, Wv, bv, uvec, vvec,
                                            Qu, Qv, KT, V);
    scores_ctx_kernel<<<BB * (LL / 16) * HH, 512, 0, stream>>>(Qu, Qv, KT, rel_table,
                                                               mk, dist, V, attn, C);
    outproj_kernel<<<BB * LL / 4, 256, 0, stream>>>(C, Wo, bo, out);
}

// Round 15
// 182.750 us; speedup vs baseline: 3.1900x; 1.0963x over previous
//
#include <hip/hip_runtime.h>
#include <math.h>

#define BB 4
#define LL 512
#define DD 256
#define HH 8
#define DHH 32
#define NB 12  // BUCKETS + 1 (row 11 is the zero padding row)

typedef _Float16 half_t;
typedef __attribute__((ext_vector_type(4))) _Float16 half4;

// K1: QKV projections (round-12 exact). 8-row tiles, 768 blocks = 3 blocks/CU.
__global__ __launch_bounds__(256) void qkv_kernel(const float* __restrict__ x,
    const float* __restrict__ Wq, const float* __restrict__ bq,
    const float* __restrict__ Wk, const float* __restrict__ bk,
    const float* __restrict__ Wv, const float* __restrict__ bv,
    const float* __restrict__ uvec, const float* __restrict__ vvec,
    float* __restrict__ Qu, float* __restrict__ Qv,
    float* __restrict__ KT, float* __restrict__ V) {
    __shared__ float xs[8][DD];
    const int mat = blockIdx.x >> 8;          // 0=Q, 1=K, 2=V
    const int r0 = (blockIdx.x & 255) * 8;
    const int t = threadIdx.x;
    const int cg = t & 63, rg = t >> 6;
    const int c0 = cg * 4;
    {
        const float4* xg = (const float4*)(x + r0 * DD);
        float4* xsv = (float4*)&xs[0][0];
        xsv[t] = xg[t];
        xsv[t + 256] = xg[t + 256];
    }
    __syncthreads();
    const float* W    = (mat == 0) ? Wq : (mat == 1) ? Wk : Wv;
    const float* bias = (mat == 0) ? bq : (mat == 1) ? bk : bv;
    float acc[2][4];
#pragma unroll
    for (int r = 0; r < 2; ++r)
#pragma unroll
        for (int c = 0; c < 4; ++c) acc[r][c] = bias[c0 + c];
    for (int i0 = 0; i0 < DD; i0 += 4) {
        float4 wv4[4], xv4[2];
#pragma unroll
        for (int j = 0; j < 4; ++j) wv4[j] = *(const float4*)&W[(i0 + j) * DD + c0];
#pragma unroll
        for (int r = 0; r < 2; ++r) xv4[r] = *(const float4*)&xs[rg * 2 + r][i0];
        const float* wf = (const float*)wv4;
        const float* xf = (const float*)xv4;
#pragma unroll
        for (int r = 0; r < 2; ++r)
#pragma unroll
            for (int j = 0; j < 4; ++j)
#pragma unroll
                for (int c = 0; c < 4; ++c)
                    acc[r][c] = fmaf(xf[r * 4 + j], wf[j * 4 + c], acc[r][c]);
    }
    if (mat == 0) {
        const float s = 0.17677669529663687f;  // 1/sqrt(DH)
        const float4 u4 = *(const float4*)&uvec[c0];
        const float4 v4 = *(const float4*)&vvec[c0];
#pragma unroll
        for (int r = 0; r < 2; ++r) {
            const int row = r0 + rg * 2 + r;
            float4 q = make_float4(acc[r][0] * s, acc[r][1] * s, acc[r][2] * s, acc[r][3] * s);
            *(float4*)&Qu[row * DD + c0] = make_float4(q.x + u4.x, q.y + u4.y, q.z + u4.z, q.w + u4.w);
            *(float4*)&Qv[row * DD + c0] = make_float4(q.x + v4.x, q.y + v4.y, q.z + v4.z, q.w + v4.w);
        }
    } else if (mat == 1) {
        const int b = r0 >> 9;
        const int kb = (r0 & 511) + rg * 2;
#pragma unroll
        for (int c = 0; c < 4; ++c) {
            const int col = c0 + c;
            const int h = col >> 5, dd = col & 31;
            float* p = KT + ((long)((b * HH + h) * DHH + dd)) * LL + kb;
            p[0] = acc[0][c];
            p[1] = acc[1][c];
        }
    } else {
#pragma unroll
        for (int r = 0; r < 2; ++r)
            *(float4*)&V[(r0 + rg * 2 + r) * DD + c0] =
                make_float4(acc[r][0], acc[r][1], acc[r][2], acc[r][3]);
    }
}

// K2: fused rel-P + scores + softmax + attn write + ctx (round-12 structure).
// ONE change vs round 12: Ss stored as fp16 (16.9 KB vs 33.8) and Qv staging
// aliased into Vs -> LDS 57.3 -> ~38.3 KB -> 4 blocks/CU (was 2). Global attn
// output stays fp32-exact; only the ctx path sees fp16 quantization (~1.5e-4).
__global__ __launch_bounds__(512, 4) void scores_ctx_kernel(const float* __restrict__ Qu,
    const float* __restrict__ Qv, const float* __restrict__ KT,
    const float* __restrict__ rel_table, const int* __restrict__ mask,
    const int* __restrict__ dist, const float* __restrict__ V,
    float* __restrict__ attn, float* __restrict__ ctx) {
    __shared__ float Qs[16][DHH];
    __shared__ float rels[NB][DHH + 1];
    __shared__ float Ps[16][NB];
    __shared__ half_t Ss[16][4][132];   // attn tile fp16, 4 k-chunks of 128 (+pad)
    __shared__ float Vs[DHH][133];      // V chunk [d][k] (+pad); rows 0..3 reused
                                        // as Qv staging in the preamble (barriered)
    float (*Qvs)[DHH] = (float (*)[DHH])&Vs[0][0];   // 16x32 floats = 2 KB alias
    const int blk = blockIdx.x;         // ((b*32 + qt)*8 + h)
    const int h = blk & 7;
    const int rest = blk >> 3;
    const int qt = rest & 31;
    const int b = rest >> 5;
    const int q0 = qt * 16;
    const int t = threadIdx.x;
    const int w = t >> 6, l = t & 63;

    {
        const int r = t >> 5, c = t & 31;
        Qs[r][c]  = Qu[(b * LL + q0 + r) * DD + h * DHH + c];
        Qvs[r][c] = Qv[(b * LL + q0 + r) * DD + h * DHH + c];
    }
    if (t < NB * DHH) {
        rels[t >> 5][t & 31] = rel_table[(t >> 5) * DD + h * DHH + (t & 31)];
    }
    __syncthreads();
    if (t < 16 * NB) {                  // Ps[r][bk] = dot32(Qv[r], rels[bk])
        const int bk = t >> 4, r = t & 15;
        float a = 0.f;
#pragma unroll
        for (int d = 0; d < DHH; ++d) a = fmaf(Qvs[r][d], rels[bk][d], a);
        Ps[r][bk] = a;
    }
    __syncthreads();

    // ---- Phase A: scores + softmax for this wave's 2 q rows (round-12 exact) ----
    const int r0 = 2 * w;
    const long kbase = (long)(b * HH + h) * DHH * LL;
    float e0[2][4], e1[2][4];
    float sum0 = 0.f, sum1 = 0.f;
#pragma unroll
    for (int s = 0; s < 2; ++s) {
        const int k0 = 4 * l + 256 * s;
        const int4 dx0 = *(const int4*)&dist[(b * LL + q0 + r0) * LL + k0];
        const int4 dx1 = *(const int4*)&dist[(b * LL + q0 + r0 + 1) * LL + k0];
        const int4 mx0 = *(const int4*)&mask[(b * LL + q0 + r0) * LL + k0];
        const int4 mx1 = *(const int4*)&mask[(b * LL + q0 + r0 + 1) * LL + k0];
        float s0[4], s1[4];
        s0[0] = Ps[r0][dx0.x]; s0[1] = Ps[r0][dx0.y]; s0[2] = Ps[r0][dx0.z]; s0[3] = Ps[r0][dx0.w];
        s1[0] = Ps[r0 + 1][dx1.x]; s1[1] = Ps[r0 + 1][dx1.y]; s1[2] = Ps[r0 + 1][dx1.z]; s1[3] = Ps[r0 + 1][dx1.w];
#pragma unroll
        for (int d8 = 0; d8 < DHH; d8 += 8) {
            float4 kv[8];                        // 8 loads in flight
#pragma unroll
            for (int j = 0; j < 8; ++j)
                kv[j] = *(const float4*)&KT[kbase + (long)(d8 + j) * LL + k0];
            const float4 q0a = *(const float4*)&Qs[r0][d8];
            const float4 q0b = *(const float4*)&Qs[r0][d8 + 4];
            const float4 q1a = *(const float4*)&Qs[r0 + 1][d8];
            const float4 q1b = *(const float4*)&Qs[r0 + 1][d8 + 4];
            const float* qa0 = (const float*)&q0a;
            const float* qb0 = (const float*)&q0b;
            const float* qa1 = (const float*)&q1a;
            const float* qb1 = (const float*)&q1b;
#pragma unroll
            for (int j = 0; j < 4; ++j) {
                s0[0] = fmaf(qa0[j], kv[j].x, s0[0]);
                s0[1] = fmaf(qa0[j], kv[j].y, s0[1]);
                s0[2] = fmaf(qa0[j], kv[j].z, s0[2]);
                s0[3] = fmaf(qa0[j], kv[j].w, s0[3]);
                s1[0] = fmaf(qa1[j], kv[j].x, s1[0]);
                s1[1] = fmaf(qa1[j], kv[j].y, s1[1]);
                s1[2] = fmaf(qa1[j], kv[j].z, s1[2]);
                s1[3] = fmaf(qa1[j], kv[j].w, s1[3]);
            }
#pragma unroll
            for (int j = 0; j < 4; ++j) {
                s0[0] = fmaf(qb0[j], kv[j + 4].x, s0[0]);
                s0[1] = fmaf(qb0[j], kv[j + 4].y, s0[1]);
                s0[2] = fmaf(qb0[j], kv[j + 4].z, s0[2]);
                s0[3] = fmaf(qb0[j], kv[j + 4].w, s0[3]);
                s1[0] = fmaf(qb1[j], kv[j + 4].x, s1[0]);
                s1[1] = fmaf(qb1[j], kv[j + 4].y, s1[1]);
                s1[2] = fmaf(qb1[j], kv[j + 4].z, s1[2]);
                s1[3] = fmaf(qb1[j], kv[j + 4].w, s1[3]);
            }
        }
        e0[s][0] = mx0.x ? 0.f : __expf(s0[0]);
        e0[s][1] = mx0.y ? 0.f : __expf(s0[1]);
        e0[s][2] = mx0.z ? 0.f : __expf(s0[2]);
        e0[s][3] = mx0.w ? 0.f : __expf(s0[3]);
        e1[s][0] = mx1.x ? 0.f : __expf(s1[0]);
        e1[s][1] = mx1.y ? 0.f : __expf(s1[1]);
        e1[s][2] = mx1.z ? 0.f : __expf(s1[2]);
        e1[s][3] = mx1.w ? 0.f : __expf(s1[3]);
        sum0 += (e0[s][0] + e0[s][1]) + (e0[s][2] + e0[s][3]);
        sum1 += (e1[s][0] + e1[s][1]) + (e1[s][2] + e1[s][3]);
    }
    for (int off = 32; off > 0; off >>= 1) {
        sum0 += __shfl_xor(sum0, off);
        sum1 += __shfl_xor(sum1, off);
    }
    const float i0 = 1.0f / sum0, i1 = 1.0f / sum1;
    float* a0 = attn + ((long)(b * HH + h) * LL + q0 + r0) * LL;
    float* a1 = a0 + LL;
#pragma unroll
    for (int s = 0; s < 2; ++s) {
        const int k0 = 4 * l + 256 * s;
        const int ch = k0 >> 7, off = k0 & 127;
        const float4 o0 = make_float4(e0[s][0] * i0, e0[s][1] * i0, e0[s][2] * i0, e0[s][3] * i0);
        const float4 o1 = make_float4(e1[s][0] * i1, e1[s][1] * i1, e1[s][2] * i1, e1[s][3] * i1);
        *(float4*)&a0[k0] = o0;                   // fp32 attn output (exact)
        *(float4*)&a1[k0] = o1;
        half4 h0 = {(half_t)o0.x, (half_t)o0.y, (half_t)o0.z, (half_t)o0.w};
        half4 h1 = {(half_t)o1.x, (half_t)o1.y, (half_t)o1.z, (half_t)o1.w};
        *(half4*)&Ss[r0][ch][off] = h0;           // fp16 tile for phase B
        *(half4*)&Ss[r0 + 1][ch][off] = h1;
    }

    // ---- Phase B: ctx via LDS-staged V chunks ----
    const int qB = t >> 5;              // 0..15
    const int dB = t & 31;
    const int kkS = t >> 2;             // staging row 0..127
    const int dqS = (t & 3) * 8;        // staging d-group of 8
    float acc = 0.f;
    for (int c = 0; c < 4; ++c) {
        __syncthreads();                // prev compute done (Ss/Qvs-alias safe)
        {   // stage V[b][c*128+kk][h*32+dq..dq+7] -> Vs[d][kk] (transposed)
            const float* vg = V + ((long)(b * LL + c * 128 + kkS)) * DD + h * DHH + dqS;
            const float4 va = *(const float4*)&vg[0];
            const float4 vb4 = *(const float4*)&vg[4];
            Vs[dqS + 0][kkS] = va.x;  Vs[dqS + 1][kkS] = va.y;
            Vs[dqS + 2][kkS] = va.z;  Vs[dqS + 3][kkS] = va.w;
            Vs[dqS + 4][kkS] = vb4.x; Vs[dqS + 5][kkS] = vb4.y;
            Vs[dqS + 6][kkS] = vb4.z; Vs[dqS + 7][kkS] = vb4.w;
        }
        __syncthreads();
#pragma unroll
        for (int j = 0; j < 32; ++j) {  // 4 k per iter
            const half4 hv = *(const half4*)&Ss[qB][c][4 * j];     // wave-broadcast b64
            const float4 vv = *(const float4*)&Vs[dB][4 * j];      // conflict-free (pad 133)
            acc = fmaf((float)hv[0], vv.x, fmaf((float)hv[1], vv.y,
                  fmaf((float)hv[2], vv.z, fmaf((float)hv[3], vv.w, acc))));
        }
    }
    ctx[(b * LL + q0 + qB) * DD + h * DHH + dB] = acc;
}

// K3: output projection (round-12 exact). Block = 4 rows; thread = 1 row x 4 cols.
__global__ __launch_bounds__(256) void outproj_kernel(const float* __restrict__ ctx,
    const float* __restrict__ Wo, const float* __restrict__ bo,
    float* __restrict__ out) {
    __shared__ float xs[4][DD];
    const int r0 = blockIdx.x * 4;
    const int t = threadIdx.x;
    const int rg = t >> 6;
    const int c0 = (t & 63) * 4;
    ((float4*)&xs[0][0])[t] = ((const float4*)(ctx + r0 * DD))[t];
    __syncthreads();
    float4 acc = *(const float4*)&bo[c0];
    for (int i0 = 0; i0 < DD; i0 += 8) {
        float4 wv[8];
#pragma unroll
        for (int j = 0; j < 8; ++j) wv[j] = *(const float4*)&Wo[(i0 + j) * DD + c0];
        const float4 x0 = *(const float4*)&xs[rg][i0];
        const float4 x1 = *(const float4*)&xs[rg][i0 + 4];
        const float* xf0 = (const float*)&x0;
        const float* xf1 = (const float*)&x1;
#pragma unroll
        for (int j = 0; j < 4; ++j) {
            acc.x = fmaf(xf0[j], wv[j].x, acc.x);
            acc.y = fmaf(xf0[j], wv[j].y, acc.y);
            acc.z = fmaf(xf0[j], wv[j].z, acc.z);
            acc.w = fmaf(xf0[j], wv[j].w, acc.w);
        }
#pragma unroll
        for (int j = 0; j < 4; ++j) {
            acc.x = fmaf(xf1[j], wv[j + 4].x, acc.x);
            acc.y = fmaf(xf1[j], wv[j + 4].y, acc.y);
            acc.z = fmaf(xf1[j], wv[j + 4].z, acc.z);
            acc.w = fmaf(xf1[j], wv[j + 4].w, acc.w);
        }
    }
    *(float4*)&out[(r0 + rg) * DD + c0] = acc;
}

extern "C" void kernel_launch(void* const* d_in, const int* in_sizes, int n_in,
                              void* d_out, int out_size, void* d_ws, size_t ws_size,
                              hipStream_t stream) {
    const float* x    = (const float*)d_in[0];
    const int* mk     = (const int*)d_in[1];   // jax bool -> int32
    const int* dist   = (const int*)d_in[2];
    const float* Wq = (const float*)d_in[3];
    const float* bq = (const float*)d_in[4];
    const float* Wk = (const float*)d_in[5];
    const float* bk = (const float*)d_in[6];
    const float* Wv = (const float*)d_in[7];
    const float* bv = (const float*)d_in[8];
    const float* Wo = (const float*)d_in[9];
    const float* bo = (const float*)d_in[10];
    const float* rel_table = (const float*)d_in[11];
    const float* uvec = (const float*)d_in[12];
    const float* vvec = (const float*)d_in[13];

    float* out  = (float*)d_out;                 // (B,L,D)
    float* attn = out + BB * LL * DD;            // (B,H,L,L)

    float* Qu = (float*)d_ws;                    // q/sqrt(dh) + u
    float* Qv = Qu + BB * LL * DD;               // q/sqrt(dh) + v
    float* KT = Qv + BB * LL * DD;               // [B][H][DH][L]
    float* V  = KT + BB * LL * DD;               // [B][L][D]
    float* C  = V + BB * LL * DD;                // ctx (B,L,D); 10.5 MB ws total

    qkv_kernel<<<3 * 256, 256, 0, stream>>>(x, Wq, bq, Wk, bk, Wv, bv, uvec, vvec,
                                            Qu, Qv, KT, V);
    scores_ctx_kernel<<<BB * (LL / 16) * HH, 512, 0, stream>>>(Qu, Qv, KT, rel_table,
                                                               mk, dist, V, attn, C);
    outproj_kernel<<<BB * LL / 4, 256, 0, stream>>>(C, Wo, bo, out);
}

// Round 16
// 180.110 us; speedup vs baseline: 3.2368x; 1.0147x over previous
//
#include <hip/hip_runtime.h>
#include <math.h>

#define BB 4
#define LL 512
#define DD 256
#define HH 8
#define DHH 32
#define NB 12  // BUCKETS + 1 (row 11 is the zero padding row)

typedef _Float16 half_t;
typedef __attribute__((ext_vector_type(4))) _Float16 half4;
typedef __attribute__((ext_vector_type(8))) _Float16 half8;

// K1: QKV projections. 8-row tiles, 768 blocks = 3 blocks/CU.
// W loads batched 8-deep (double the in-flight L2 lines vs round 12/15).
__global__ __launch_bounds__(256) void qkv_kernel(const float* __restrict__ x,
    const float* __restrict__ Wq, const float* __restrict__ bq,
    const float* __restrict__ Wk, const float* __restrict__ bk,
    const float* __restrict__ Wv, const float* __restrict__ bv,
    const float* __restrict__ uvec, const float* __restrict__ vvec,
    float* __restrict__ Qu, float* __restrict__ Qv,
    float* __restrict__ KT, float* __restrict__ V) {
    __shared__ float xs[8][DD];
    const int mat = blockIdx.x >> 8;          // 0=Q, 1=K, 2=V
    const int r0 = (blockIdx.x & 255) * 8;
    const int t = threadIdx.x;
    const int cg = t & 63, rg = t >> 6;
    const int c0 = cg * 4;
    {
        const float4* xg = (const float4*)(x + r0 * DD);
        float4* xsv = (float4*)&xs[0][0];
        xsv[t] = xg[t];
        xsv[t + 256] = xg[t + 256];
    }
    __syncthreads();
    const float* W    = (mat == 0) ? Wq : (mat == 1) ? Wk : Wv;
    const float* bias = (mat == 0) ? bq : (mat == 1) ? bk : bv;
    float acc[2][4];
#pragma unroll
    for (int r = 0; r < 2; ++r)
#pragma unroll
        for (int c = 0; c < 4; ++c) acc[r][c] = bias[c0 + c];
    for (int i0 = 0; i0 < DD; i0 += 8) {
        float4 wv4[8], xa[2], xb[2];
#pragma unroll
        for (int j = 0; j < 8; ++j) wv4[j] = *(const float4*)&W[(i0 + j) * DD + c0];
#pragma unroll
        for (int r = 0; r < 2; ++r) {
            xa[r] = *(const float4*)&xs[rg * 2 + r][i0];
            xb[r] = *(const float4*)&xs[rg * 2 + r][i0 + 4];
        }
#pragma unroll
        for (int r = 0; r < 2; ++r) {
            const float* xf = (const float*)&xa[r];
            const float* xg2 = (const float*)&xb[r];
#pragma unroll
            for (int j = 0; j < 4; ++j)
#pragma unroll
                for (int c = 0; c < 4; ++c)
                    acc[r][c] = fmaf(xf[j], ((const float*)&wv4[j])[c], acc[r][c]);
#pragma unroll
            for (int j = 0; j < 4; ++j)
#pragma unroll
                for (int c = 0; c < 4; ++c)
                    acc[r][c] = fmaf(xg2[j], ((const float*)&wv4[j + 4])[c], acc[r][c]);
        }
    }
    if (mat == 0) {
        const float s = 0.17677669529663687f;  // 1/sqrt(DH)
        const float4 u4 = *(const float4*)&uvec[c0];
        const float4 v4 = *(const float4*)&vvec[c0];
#pragma unroll
        for (int r = 0; r < 2; ++r) {
            const int row = r0 + rg * 2 + r;
            float4 q = make_float4(acc[r][0] * s, acc[r][1] * s, acc[r][2] * s, acc[r][3] * s);
            *(float4*)&Qu[row * DD + c0] = make_float4(q.x + u4.x, q.y + u4.y, q.z + u4.z, q.w + u4.w);
            *(float4*)&Qv[row * DD + c0] = make_float4(q.x + v4.x, q.y + v4.y, q.z + v4.z, q.w + v4.w);
        }
    } else if (mat == 1) {
        const int b = r0 >> 9;
        const int kb = (r0 & 511) + rg * 2;
#pragma unroll
        for (int c = 0; c < 4; ++c) {
            const int col = c0 + c;
            const int h = col >> 5, dd = col & 31;
            float* p = KT + ((long)((b * HH + h) * DHH + dd)) * LL + kb;
            p[0] = acc[0][c];
            p[1] = acc[1][c];
        }
    } else {
#pragma unroll
        for (int r = 0; r < 2; ++r)
            *(float4*)&V[(r0 + rg * 2 + r) * DD + c0] =
                make_float4(acc[r][0], acc[r][1], acc[r][2], acc[r][3]);
    }
}

// K2: fused rel-P + scores + softmax + attn write + ctx (round-15 structure).
// Change vs r15: Ss chunk stride 132 -> 136 halves (16B-aligned) so phase B reads
// Ss as b128 (8 k / instr): inner loop 48 LDS reads per chunk (was 64).
__global__ __launch_bounds__(512, 4) void scores_ctx_kernel(const float* __restrict__ Qu,
    const float* __restrict__ Qv, const float* __restrict__ KT,
    const float* __restrict__ rel_table, const int* __restrict__ mask,
    const int* __restrict__ dist, const float* __restrict__ V,
    float* __restrict__ attn, float* __restrict__ ctx) {
    __shared__ float Qs[16][DHH];
    __shared__ float rels[NB][DHH + 1];
    __shared__ float Ps[16][NB];
    __shared__ half_t Ss[16][4][136];   // attn tile fp16; chunk stride 136 (16B align)
    __shared__ float Vs[DHH][133];      // V chunk [d][k] (+pad); rows 0..3 reused
                                        // as Qv staging in the preamble (barriered)
    float (*Qvs)[DHH] = (float (*)[DHH])&Vs[0][0];   // 16x32 floats = 2 KB alias
    const int blk = blockIdx.x;         // ((b*32 + qt)*8 + h)
    const int h = blk & 7;
    const int rest = blk >> 3;
    const int qt = rest & 31;
    const int b = rest >> 5;
    const int q0 = qt * 16;
    const int t = threadIdx.x;
    const int w = t >> 6, l = t & 63;

    {
        const int r = t >> 5, c = t & 31;
        Qs[r][c]  = Qu[(b * LL + q0 + r) * DD + h * DHH + c];
        Qvs[r][c] = Qv[(b * LL + q0 + r) * DD + h * DHH + c];
    }
    if (t < NB * DHH) {
        rels[t >> 5][t & 31] = rel_table[(t >> 5) * DD + h * DHH + (t & 31)];
    }
    __syncthreads();
    if (t < 16 * NB) {                  // Ps[r][bk] = dot32(Qv[r], rels[bk])
        const int bk = t >> 4, r = t & 15;
        float a = 0.f;
#pragma unroll
        for (int d = 0; d < DHH; ++d) a = fmaf(Qvs[r][d], rels[bk][d], a);
        Ps[r][bk] = a;
    }
    __syncthreads();

    // ---- Phase A: scores + softmax for this wave's 2 q rows ----
    const int r0 = 2 * w;
    const long kbase = (long)(b * HH + h) * DHH * LL;
    float e0[2][4], e1[2][4];
    float sum0 = 0.f, sum1 = 0.f;
#pragma unroll
    for (int s = 0; s < 2; ++s) {
        const int k0 = 4 * l + 256 * s;
        const int4 dx0 = *(const int4*)&dist[(b * LL + q0 + r0) * LL + k0];
        const int4 dx1 = *(const int4*)&dist[(b * LL + q0 + r0 + 1) * LL + k0];
        const int4 mx0 = *(const int4*)&mask[(b * LL + q0 + r0) * LL + k0];
        const int4 mx1 = *(const int4*)&mask[(b * LL + q0 + r0 + 1) * LL + k0];
        float s0[4], s1[4];
        s0[0] = Ps[r0][dx0.x]; s0[1] = Ps[r0][dx0.y]; s0[2] = Ps[r0][dx0.z]; s0[3] = Ps[r0][dx0.w];
        s1[0] = Ps[r0 + 1][dx1.x]; s1[1] = Ps[r0 + 1][dx1.y]; s1[2] = Ps[r0 + 1][dx1.z]; s1[3] = Ps[r0 + 1][dx1.w];
#pragma unroll
        for (int d8 = 0; d8 < DHH; d8 += 8) {
            float4 kv[8];                        // 8 loads in flight
#pragma unroll
            for (int j = 0; j < 8; ++j)
                kv[j] = *(const float4*)&KT[kbase + (long)(d8 + j) * LL + k0];
            const float4 q0a = *(const float4*)&Qs[r0][d8];
            const float4 q0b = *(const float4*)&Qs[r0][d8 + 4];
            const float4 q1a = *(const float4*)&Qs[r0 + 1][d8];
            const float4 q1b = *(const float4*)&Qs[r0 + 1][d8 + 4];
            const float* qa0 = (const float*)&q0a;
            const float* qb0 = (const float*)&q0b;
            const float* qa1 = (const float*)&q1a;
            const float* qb1 = (const float*)&q1b;
#pragma unroll
            for (int j = 0; j < 4; ++j) {
                s0[0] = fmaf(qa0[j], kv[j].x, s0[0]);
                s0[1] = fmaf(qa0[j], kv[j].y, s0[1]);
                s0[2] = fmaf(qa0[j], kv[j].z, s0[2]);
                s0[3] = fmaf(qa0[j], kv[j].w, s0[3]);
                s1[0] = fmaf(qa1[j], kv[j].x, s1[0]);
                s1[1] = fmaf(qa1[j], kv[j].y, s1[1]);
                s1[2] = fmaf(qa1[j], kv[j].z, s1[2]);
                s1[3] = fmaf(qa1[j], kv[j].w, s1[3]);
            }
#pragma unroll
            for (int j = 0; j < 4; ++j) {
                s0[0] = fmaf(qb0[j], kv[j + 4].x, s0[0]);
                s0[1] = fmaf(qb0[j], kv[j + 4].y, s0[1]);
                s0[2] = fmaf(qb0[j], kv[j + 4].z, s0[2]);
                s0[3] = fmaf(qb0[j], kv[j + 4].w, s0[3]);
                s1[0] = fmaf(qb1[j], kv[j + 4].x, s1[0]);
                s1[1] = fmaf(qb1[j], kv[j + 4].y, s1[1]);
                s1[2] = fmaf(qb1[j], kv[j + 4].z, s1[2]);
                s1[3] = fmaf(qb1[j], kv[j + 4].w, s1[3]);
            }
        }
        e0[s][0] = mx0.x ? 0.f : __expf(s0[0]);
        e0[s][1] = mx0.y ? 0.f : __expf(s0[1]);
        e0[s][2] = mx0.z ? 0.f : __expf(s0[2]);
        e0[s][3] = mx0.w ? 0.f : __expf(s0[3]);
        e1[s][0] = mx1.x ? 0.f : __expf(s1[0]);
        e1[s][1] = mx1.y ? 0.f : __expf(s1[1]);
        e1[s][2] = mx1.z ? 0.f : __expf(s1[2]);
        e1[s][3] = mx1.w ? 0.f : __expf(s1[3]);
        sum0 += (e0[s][0] + e0[s][1]) + (e0[s][2] + e0[s][3]);
        sum1 += (e1[s][0] + e1[s][1]) + (e1[s][2] + e1[s][3]);
    }
    for (int off = 32; off > 0; off >>= 1) {
        sum0 += __shfl_xor(sum0, off);
        sum1 += __shfl_xor(sum1, off);
    }
    const float i0 = 1.0f / sum0, i1 = 1.0f / sum1;
    float* a0 = attn + ((long)(b * HH + h) * LL + q0 + r0) * LL;
    float* a1 = a0 + LL;
#pragma unroll
    for (int s = 0; s < 2; ++s) {
        const int k0 = 4 * l + 256 * s;
        const int ch = k0 >> 7, off = k0 & 127;
        const float4 o0 = make_float4(e0[s][0] * i0, e0[s][1] * i0, e0[s][2] * i0, e0[s][3] * i0);
        const float4 o1 = make_float4(e1[s][0] * i1, e1[s][1] * i1, e1[s][2] * i1, e1[s][3] * i1);
        *(float4*)&a0[k0] = o0;                   // fp32 attn output (exact)
        *(float4*)&a1[k0] = o1;
        half4 h0 = {(half_t)o0.x, (half_t)o0.y, (half_t)o0.z, (half_t)o0.w};
        half4 h1 = {(half_t)o1.x, (half_t)o1.y, (half_t)o1.z, (half_t)o1.w};
        *(half4*)&Ss[r0][ch][off] = h0;           // 8B-aligned (off mult of 4)
        *(half4*)&Ss[r0 + 1][ch][off] = h1;
    }

    // ---- Phase B: ctx via LDS-staged V chunks ----
    const int qB = t >> 5;              // 0..15
    const int dB = t & 31;
    const int kkS = t >> 2;             // staging row 0..127
    const int dqS = (t & 3) * 8;        // staging d-group of 8
    float acc = 0.f;
    for (int c = 0; c < 4; ++c) {
        __syncthreads();                // prev compute done (Ss/Qvs-alias safe)
        {   // stage V[b][c*128+kk][h*32+dq..dq+7] -> Vs[d][kk] (transposed)
            const float* vg = V + ((long)(b * LL + c * 128 + kkS)) * DD + h * DHH + dqS;
            const float4 va = *(const float4*)&vg[0];
            const float4 vb4 = *(const float4*)&vg[4];
            Vs[dqS + 0][kkS] = va.x;  Vs[dqS + 1][kkS] = va.y;
            Vs[dqS + 2][kkS] = va.z;  Vs[dqS + 3][kkS] = va.w;
            Vs[dqS + 4][kkS] = vb4.x; Vs[dqS + 5][kkS] = vb4.y;
            Vs[dqS + 6][kkS] = vb4.z; Vs[dqS + 7][kkS] = vb4.w;
        }
        __syncthreads();
#pragma unroll
        for (int j = 0; j < 16; ++j) {  // 8 k per iter: 1 Ss b128 + 2 Vs b128
            const half8 hv = *(const half8*)&Ss[qB][c][8 * j];     // broadcast b128
            const float4 v0 = *(const float4*)&Vs[dB][8 * j];      // conflict-free
            const float4 v1 = *(const float4*)&Vs[dB][8 * j + 4];
            acc = fmaf((float)hv[0], v0.x, fmaf((float)hv[1], v0.y,
                  fmaf((float)hv[2], v0.z, fmaf((float)hv[3], v0.w, acc))));
            acc = fmaf((float)hv[4], v1.x, fmaf((float)hv[5], v1.y,
                  fmaf((float)hv[6], v1.z, fmaf((float)hv[7], v1.w, acc))));
        }
    }
    ctx[(b * LL + q0 + qB) * DD + h * DHH + dB] = acc;
}

// K3: output projection (round-12 exact). Block = 4 rows; thread = 1 row x 4 cols.
__global__ __launch_bounds__(256) void outproj_kernel(const float* __restrict__ ctx,
    const float* __restrict__ Wo, const float* __restrict__ bo,
    float* __restrict__ out) {
    __shared__ float xs[4][DD];
    const int r0 = blockIdx.x * 4;
    const int t = threadIdx.x;
    const int rg = t >> 6;
    const int c0 = (t & 63) * 4;
    ((float4*)&xs[0][0])[t] = ((const float4*)(ctx + r0 * DD))[t];
    __syncthreads();
    float4 acc = *(const float4*)&bo[c0];
    for (int i0 = 0; i0 < DD; i0 += 8) {
        float4 wv[8];
#pragma unroll
        for (int j = 0; j < 8; ++j) wv[j] = *(const float4*)&Wo[(i0 + j) * DD + c0];
        const float4 x0 = *(const float4*)&xs[rg][i0];
        const float4 x1 = *(const float4*)&xs[rg][i0 + 4];
        const float* xf0 = (const float*)&x0;
        const float* xf1 = (const float*)&x1;
#pragma unroll
        for (int j = 0; j < 4; ++j) {
            acc.x = fmaf(xf0[j], wv[j].x, acc.x);
            acc.y = fmaf(xf0[j], wv[j].y, acc.y);
            acc.z = fmaf(xf0[j], wv[j].z, acc.z);
            acc.w = fmaf(xf0[j], wv[j].w, acc.w);
        }
#pragma unroll
        for (int j = 0; j < 4; ++j) {
            acc.x = fmaf(xf1[j], wv[j + 4].x, acc.x);
            acc.y = fmaf(xf1[j], wv[j + 4].y, acc.y);
            acc.z = fmaf(xf1[j], wv[j + 4].z, acc.z);
            acc.w = fmaf(xf1[j], wv[j + 4].w, acc.w);
        }
    }
    *(float4*)&out[(r0 + rg) * DD + c0] = acc;
}

extern "C" void kernel_launch(void* const* d_in, const int* in_sizes, int n_in,
                              void* d_out, int out_size, void* d_ws, size_t ws_size,
                              hipStream_t stream) {
    const float* x    = (const float*)d_in[0];
    const int* mk     = (const int*)d_in[1];   // jax bool -> int32
    const int* dist   = (const int*)d_in[2];
    const float* Wq = (const float*)d_in[3];
    const float* bq = (const float*)d_in[4];
    const float* Wk = (const float*)d_in[5];
    const float* bk = (const float*)d_in[6];
    const float* Wv = (const float*)d_in[7];
    const float* bv = (const float*)d_in[8];
    const float* Wo = (const float*)d_in[9];
    const float* bo = (const float*)d_in[10];
    const float* rel_table = (const float*)d_in[11];
    const float* uvec = (const float*)d_in[12];
    const float* vvec = (const float*)d_in[13];

    float* out  = (float*)d_out;                 // (B,L,D)
    float* attn = out + BB * LL * DD;            // (B,H,L,L)

    float* Qu = (float*)d_ws;                    // q/sqrt(dh) + u
    float* Qv = Qu + BB * LL * DD;               // q/sqrt(dh) + v
    float* KT = Qv + BB * LL * DD;               // [B][H][DH][L]
    float* V  = KT + BB * LL * DD;               // [B][L][D]
    float* C  = V + BB * LL * DD;                // ctx (B,L,D); 10.5 MB ws total

    qkv_kernel<<<3 * 256, 256, 0, stream>>>(x, Wq, bq, Wk, bk, Wv, bv, uvec, vvec,
                                            Qu, Qv, KT, V);
    scores_ctx_kernel<<<BB * (LL / 16) * HH, 512, 0, stream>>>(Qu, Qv, KT, rel_table,
                                                               mk, dist, V, attn, C);
    outproj_kernel<<<BB * LL / 4, 256, 0, stream>>>(C, Wo, bo, out);
}